// Round 10
// baseline (854.550 us; speedup 1.0000x reference)
//
#include <hip/hip_runtime.h>
#include <hip/hip_fp16.h>

#define NS 20000
#define NM 100000
#define H  128
#define ES 1000000
#define EM 2000000
#define EL 500000

#define SH_M 7
#define SH_S 6
#define NB_SD 782
#define NB_SS 313
#define NB_MD 782
#define NB_MS 782
#define CAP_SD 1664
#define CAP_SS 3904
#define CAP_MD 3200
#define CAP_MS 3200
#define MAXCAP 3904
#define CHUNK 4096
#define B_SD ((ES + CHUNK - 1) / CHUNK)
#define B_SS ((ES + CHUNK - 1) / CHUNK)
#define B_MD ((EM + CHUNK - 1) / CHUNK)
#define B_MS ((EM + CHUNK - 1) / CHUNK)
#define VAL_MASK 0x1FFFF

// fused layer geometry (R4-proven): 16 output rows per block, barrier structure
#define MB_M (NM / 16)     // 6250
#define MB_S (NS / 16)     // 1250
#define APAD 136           // LDS A-tile row stride in halves

// merged place1+prep grid sections
#define P1_BLKS (B_SD + B_SS + B_MD + B_MS)   // 1468 sort blocks
#define PB_M 12500         // NM*H/4 / 256
#define PB_S 2500          // NS*H/4 / 256
#define PB_W 768           // 12*H*H / 256

// sage_sd + finalize grid sections
#define SD_GBLK (NM * 16 / 256)    // 6250
#define FIN_BLK ((NM + 255) / 256) // 391

// degree-bin permutation grids
#define HB_M ((NM + 255) / 256)    // 391
#define HB_S ((NS + 255) / 256)    // 79

typedef _Float16 half8 __attribute__((ext_vector_type(8)));
typedef float floatx4 __attribute__((ext_vector_type(4)));

// ---------------- CSR build phase 1 + independent prep work in one dispatch ----------------
__global__ __launch_bounds__(256) void place1_prep(
        const int* __restrict__ s2m_src, const int* __restrict__ s2m_dst,
        const int* __restrict__ m2m_src, const int* __restrict__ m2m_dst,
        int* __restrict__ bc,
        unsigned int* __restrict__ p_sd, unsigned int* __restrict__ p_ss,
        unsigned int* __restrict__ p_md, unsigned int* __restrict__ p_ms,
        const float* __restrict__ m_emb, const float* __restrict__ s_emb,
        const float* __restrict__ w0, const float* __restrict__ w1,
        const float* __restrict__ w2, const float* __restrict__ w3,
        const float* __restrict__ w4, const float* __restrict__ w5,
        __half* __restrict__ xm16, __half* __restrict__ xs16,
        __half* __restrict__ wbuf) {
    __shared__ unsigned int rec[CHUNK];
    __shared__ unsigned short eb[CHUNK];
    __shared__ int cnt[1024];
    __shared__ int gbase[1024];

    int b = blockIdx.x;
    int t = threadIdx.x;

    if (b >= P1_BLKS) {
        int pb = b - P1_BLKS;
        if (pb < PB_M) {
            long long i = (long long)pb * 256 + t;
            float4 v = *(const float4*)&m_emb[i * 4];
            __half2 h0 = __floats2half2_rn(v.x, v.y);
            __half2 h1 = __floats2half2_rn(v.z, v.w);
            __half2* o = (__half2*)&xm16[i * 4];
            o[0] = h0; o[1] = h1;
        } else if (pb < PB_M + PB_S) {
            long long i = (long long)(pb - PB_M) * 256 + t;
            float4 v = *(const float4*)&s_emb[i * 4];
            __half2 h0 = __floats2half2_rn(v.x, v.y);
            __half2 h1 = __floats2half2_rn(v.z, v.w);
            __half2* o = (__half2*)&xs16[i * 4];
            o[0] = h0; o[1] = h1;
        } else {
            int idx = (pb - PB_M - PB_S) * 256 + t;
            int mat = idx / (H * H);
            int rem = idx % (H * H);
            int n = rem / H;
            int k = rem % H;
            const float* base;
            switch (mat >> 1) {
            case 0: base = w0; break; case 1: base = w1; break; case 2: base = w2; break;
            case 3: base = w3; break; case 4: base = w4; break; default: base = w5; break;
            }
            base += (size_t)(mat & 1) * H * H;
            wbuf[(size_t)mat * H * H + (size_t)n * H + k] = __float2half(base[(size_t)k * H + n]);
        }
        return;
    }

    const int *keys, *vals; int shift, cap, E, bcoff; unsigned int* pp;
    int cb;
    if (b < B_SD)                    { cb = b;                      keys = s2m_dst; vals = s2m_src; shift = SH_M; cap = CAP_SD; E = ES; bcoff = 0;     pp = p_sd; }
    else if (b < B_SD+B_SS)          { cb = b - B_SD;               keys = s2m_src; vals = s2m_dst; shift = SH_S; cap = CAP_SS; E = ES; bcoff = 16384; pp = p_ss; }
    else if (b < B_SD+B_SS+B_MD)     { cb = b - B_SD - B_SS;        keys = m2m_dst; vals = m2m_src; shift = SH_M; cap = CAP_MD; E = EM; bcoff = 32768; pp = p_md; }
    else                             { cb = b - B_SD - B_SS - B_MD; keys = m2m_src; vals = m2m_dst; shift = SH_M; cap = CAP_MS; E = EM; bcoff = 49152; pp = p_ms; }
    int* bcp = bc + bcoff;

    int e0 = cb * CHUNK;
    int nv = E - e0; if (nv > CHUNK) nv = CHUNK;

    for (int i = t; i < nv; i += 256) {
        int k = keys[e0 + i];
        int v = vals[e0 + i];
        int bkt = k >> shift;
        rec[i] = ((unsigned int)(k - (bkt << shift)) << 17) | (unsigned int)v;
        eb[i] = (unsigned short)bkt;
    }
#pragma unroll
    for (int j = 0; j < 4; ++j) cnt[t * 4 + j] = 0;
    __syncthreads();
    for (int i = t; i < nv; i += 256) atomicAdd(&cnt[eb[i]], 1);
    __syncthreads();
#pragma unroll
    for (int j = 0; j < 4; ++j) {
        int bk = t * 4 + j;
        int c = cnt[bk];
        if (c > 0) {
            gbase[bk] = atomicAdd(&bcp[bk << 4], c);
            cnt[bk] = 0;
        }
    }
    __syncthreads();
    for (int i = t; i < nv; i += 256) {
        int bk = eb[i];
        int pos = atomicAdd(&cnt[bk], 1);
        int o = gbase[bk] + pos;
        if (o < cap) pp[(size_t)bk * cap + o] = rec[i];
    }
}

// phase 2: fixed-stride adjacency (bucket b owns [b*cap, ...)) — unchanged
__global__ __launch_bounds__(256) void place2_fused(
        const int* __restrict__ bc,
        const unsigned int* __restrict__ p_sd, const unsigned int* __restrict__ p_ss,
        const unsigned int* __restrict__ p_md, const unsigned int* __restrict__ p_ms,
        int* __restrict__ adj_sd, int* __restrict__ adj_ss,
        int* __restrict__ adj_md, int* __restrict__ adj_ms,
        int* __restrict__ off_sd, int* __restrict__ off_ss,
        int* __restrict__ off_md, int* __restrict__ off_ms,
        int* __restrict__ cnt_sd, int* __restrict__ cnt_ss,
        int* __restrict__ cnt_md, int* __restrict__ cnt_ms) {
    __shared__ unsigned int lp[MAXCAP];
    __shared__ int hist[128], cur[128], sbuf[128];
    int b = blockIdx.x;
    int c, lb;
    if (b < NB_SD)                    { c = 0; lb = b; }
    else if (b < NB_SD+NB_SS)         { c = 1; lb = b - NB_SD; }
    else if (b < NB_SD+NB_SS+NB_MD)   { c = 2; lb = b - NB_SD - NB_SS; }
    else                              { c = 3; lb = b - NB_SD - NB_SS - NB_MD; }
    const unsigned int* pp; int *adj, *offp, *cntp; int shift, cap, n;
    switch (c) {
    case 0:  pp = p_sd; adj = adj_sd; offp = off_sd; cntp = cnt_sd; shift = SH_M; cap = CAP_SD; n = NM; break;
    case 1:  pp = p_ss; adj = adj_ss; offp = off_ss; cntp = cnt_ss; shift = SH_S; cap = CAP_SS; n = NS; break;
    case 2:  pp = p_md; adj = adj_md; offp = off_md; cntp = cnt_md; shift = SH_M; cap = CAP_MD; n = NM; break;
    default: pp = p_ms; adj = adj_ms; offp = off_ms; cntp = cnt_ms; shift = SH_M; cap = CAP_MS; n = NM; break;
    }
    int t = threadIdx.x;
    int k = bc[c * 16384 + (lb << 4)];
    if (k > cap) k = cap;
    int base = lb << shift;
    int npb = 1 << shift;
    int bb = lb * cap;   // fixed-stride region
    for (int i = t; i < k; i += 256) lp[i] = pp[(size_t)lb * cap + i];
    if (t < npb) hist[t] = 0;
    __syncthreads();
    for (int i = t; i < k; i += 256) atomicAdd(&hist[lp[i] >> 17], 1);
    __syncthreads();
    int v = (t < npb) ? hist[t] : 0;
    if (t < 128) sbuf[t] = v;
    __syncthreads();
    for (int d = 1; d < 128; d <<= 1) {
        int x = 0;
        if (t >= d && t < 128) x = sbuf[t - d];
        __syncthreads();
        if (t >= d && t < 128) sbuf[t] += x;
        __syncthreads();
    }
    if (t < npb) {
        int excl = sbuf[t] - v;
        cur[t] = excl;
        int node = base + t;
        if (node < n) { offp[node] = bb + excl; cntp[node] = v; }
    }
    __syncthreads();
    for (int i = t; i < k; i += 256) {
        unsigned int p = lp[i];
        int pos = atomicAdd(&cur[p >> 17], 1);
        adj[(size_t)bb + pos] = (int)(p & VAL_MASK);
    }
}

// ---------------- degree-bin permutation (R1-verified mechanism, keyed for fused_layer) ----------------
// m-rows binned by cnt_md+cnt_ms (the two barrier-coupled gathers); s-rows by cnt_ss.
__global__ void bin_hist(const int* __restrict__ c_md, const int* __restrict__ c_ms,
                         const int* __restrict__ c_ss, int* __restrict__ binCnt) {
    __shared__ int lb[64];
    int b = blockIdx.x, t = threadIdx.x;
    if (t < 64) lb[t] = 0;
    __syncthreads();
    if (b < HB_M) {
        int i = b * 256 + t;
        if (i < NM) {
            int bin = (c_md[i] + c_ms[i] + 7) >> 3; if (bin > 63) bin = 63;
            atomicAdd(&lb[bin], 1);
        }
    } else {
        int i = (b - HB_M) * 256 + t;
        if (i < NS) {
            int bin = (c_ss[i] + 7) >> 3; if (bin > 63) bin = 63;
            atomicAdd(&lb[bin], 1);
        }
    }
    __syncthreads();
    int base = (b < HB_M) ? 0 : 64;
    if (t < 64 && lb[t] > 0) atomicAdd(&binCnt[base + t], lb[t]);
}

// descending-degree exclusive scan (1 block, 128 threads)
__global__ void bin_scan(const int* __restrict__ binCnt, int* __restrict__ binBase) {
    int t = threadIdx.x;          // 128
    int s = t >> 6, b2 = t & 63;
    int off = 0;
    for (int q = 63; q > b2; --q) off += binCnt[s * 64 + q];
    binBase[t] = off;
}

__global__ void bin_scatter(const int* __restrict__ c_md, const int* __restrict__ c_ms,
                            const int* __restrict__ c_ss, int* __restrict__ binBase,
                            int* __restrict__ wl_m, int* __restrict__ wl_s) {
    __shared__ int lc[64], lb[64];
    int b = blockIdx.x, t = threadIdx.x;
    if (t < 64) lc[t] = 0;
    __syncthreads();
    int bin = 0, pos = 0; bool valid = false; int i = -1;
    if (b < HB_M) {
        i = b * 256 + t;
        if (i < NM) {
            bin = (c_md[i] + c_ms[i] + 7) >> 3; if (bin > 63) bin = 63;
            pos = atomicAdd(&lc[bin], 1); valid = true;
        }
    } else {
        i = (b - HB_M) * 256 + t;
        if (i < NS) {
            bin = (c_ss[i] + 7) >> 3; if (bin > 63) bin = 63;
            pos = atomicAdd(&lc[bin], 1); valid = true;
        }
    }
    __syncthreads();
    int base = (b < HB_M) ? 0 : 64;
    if (t < 64 && lc[t] > 0) lb[t] = atomicAdd(&binBase[base + t], lc[t]);
    __syncthreads();
    if (valid) {
        if (b < HB_M) wl_m[lb[bin] + pos] = i;
        else          wl_s[lb[bin] + pos] = i;
    }
}

// ---------------- gather primitives: 16 lanes/row, half8 loads, unroll 8 (R0-proven) ----------------
__device__ __forceinline__ void gacc_plain(const __half* __restrict__ X,
                                           const int* __restrict__ adj,
                                           int o, int k, int c, float (&acc)[8]) {
    int j = 0;
    for (; j + 8 <= k; j += 8) {
        int s0 = adj[o+j+0], s1 = adj[o+j+1], s2 = adj[o+j+2], s3 = adj[o+j+3];
        int s4 = adj[o+j+4], s5 = adj[o+j+5], s6 = adj[o+j+6], s7 = adj[o+j+7];
        half8 v0 = *(const half8*)(X + (size_t)s0 * H + c);
        half8 v1 = *(const half8*)(X + (size_t)s1 * H + c);
        half8 v2 = *(const half8*)(X + (size_t)s2 * H + c);
        half8 v3 = *(const half8*)(X + (size_t)s3 * H + c);
        half8 v4 = *(const half8*)(X + (size_t)s4 * H + c);
        half8 v5 = *(const half8*)(X + (size_t)s5 * H + c);
        half8 v6 = *(const half8*)(X + (size_t)s6 * H + c);
        half8 v7 = *(const half8*)(X + (size_t)s7 * H + c);
#pragma unroll
        for (int i = 0; i < 8; ++i)
            acc[i] += (float)v0[i] + (float)v1[i] + (float)v2[i] + (float)v3[i]
                    + (float)v4[i] + (float)v5[i] + (float)v6[i] + (float)v7[i];
    }
    for (; j + 4 <= k; j += 4) {
        int s0 = adj[o+j+0], s1 = adj[o+j+1], s2 = adj[o+j+2], s3 = adj[o+j+3];
        half8 v0 = *(const half8*)(X + (size_t)s0 * H + c);
        half8 v1 = *(const half8*)(X + (size_t)s1 * H + c);
        half8 v2 = *(const half8*)(X + (size_t)s2 * H + c);
        half8 v3 = *(const half8*)(X + (size_t)s3 * H + c);
#pragma unroll
        for (int i = 0; i < 8; ++i)
            acc[i] += (float)v0[i] + (float)v1[i] + (float)v2[i] + (float)v3[i];
    }
    for (; j < k; ++j) {
        int s = adj[o + j];
        half8 v = *(const half8*)(X + (size_t)s * H + c);
#pragma unroll
        for (int i = 0; i < 8; ++i) acc[i] += (float)v[i];
    }
}

__device__ __forceinline__ void gacc_weighted(const __half* __restrict__ X,
                                              const int* __restrict__ adj,
                                              const float* __restrict__ dinv,
                                              int o, int k, int c, float (&acc)[8]) {
    int j = 0;
    for (; j + 8 <= k; j += 8) {
        int s0 = adj[o+j+0], s1 = adj[o+j+1], s2 = adj[o+j+2], s3 = adj[o+j+3];
        int s4 = adj[o+j+4], s5 = adj[o+j+5], s6 = adj[o+j+6], s7 = adj[o+j+7];
        float d0 = dinv[s0], d1 = dinv[s1], d2 = dinv[s2], d3 = dinv[s3];
        float d4 = dinv[s4], d5 = dinv[s5], d6 = dinv[s6], d7 = dinv[s7];
        half8 v0 = *(const half8*)(X + (size_t)s0 * H + c);
        half8 v1 = *(const half8*)(X + (size_t)s1 * H + c);
        half8 v2 = *(const half8*)(X + (size_t)s2 * H + c);
        half8 v3 = *(const half8*)(X + (size_t)s3 * H + c);
        half8 v4 = *(const half8*)(X + (size_t)s4 * H + c);
        half8 v5 = *(const half8*)(X + (size_t)s5 * H + c);
        half8 v6 = *(const half8*)(X + (size_t)s6 * H + c);
        half8 v7 = *(const half8*)(X + (size_t)s7 * H + c);
#pragma unroll
        for (int i = 0; i < 8; ++i)
            acc[i] += d0 * (float)v0[i] + d1 * (float)v1[i] + d2 * (float)v2[i] + d3 * (float)v3[i]
                    + d4 * (float)v4[i] + d5 * (float)v5[i] + d6 * (float)v6[i] + d7 * (float)v7[i];
    }
    for (; j + 4 <= k; j += 4) {
        int s0 = adj[o+j+0], s1 = adj[o+j+1], s2 = adj[o+j+2], s3 = adj[o+j+3];
        float d0 = dinv[s0], d1 = dinv[s1], d2 = dinv[s2], d3 = dinv[s3];
        half8 v0 = *(const half8*)(X + (size_t)s0 * H + c);
        half8 v1 = *(const half8*)(X + (size_t)s1 * H + c);
        half8 v2 = *(const half8*)(X + (size_t)s2 * H + c);
        half8 v3 = *(const half8*)(X + (size_t)s3 * H + c);
#pragma unroll
        for (int i = 0; i < 8; ++i)
            acc[i] += d0 * (float)v0[i] + d1 * (float)v1[i] + d2 * (float)v2[i] + d3 * (float)v3[i];
    }
    for (; j < k; ++j) {
        int s = adj[o + j];
        float ds = dinv[s];
        half8 v = *(const half8*)(X + (size_t)s * H + c);
#pragma unroll
        for (int i = 0; i < 8; ++i) acc[i] += ds * (float)v[i];
    }
}

__device__ __forceinline__ void st_h8(__half* p, const float (&a)[8]) {
    half8 h;
#pragma unroll
    for (int i = 0; i < 8; ++i) h[i] = (_Float16)a[i];
    *(half8*)p = h;
}

// ---------------- kernel A: SAGE s2m gather (xs only) + dinv finalize blocks ----------------
__global__ __launch_bounds__(256) void sage_sd_fin(
        const __half* __restrict__ xs_in,
        const int* __restrict__ off_sd, const int* __restrict__ cnt_sd,
        const int* __restrict__ adj_sd,
        const int* __restrict__ c_md, const int* __restrict__ c_ms,
        __half* __restrict__ SA, float* __restrict__ dvf, float* __restrict__ dvr) {
    int b = blockIdx.x, t = threadIdx.x;
    if (b >= SD_GBLK) {
        int i = (b - SD_GBLK) * 256 + t;
        if (i < NM) {
            dvf[i] = rsqrtf((float)c_md[i] + 1.0f);
            dvr[i] = rsqrtf((float)c_ms[i] + 1.0f);
        }
        return;
    }
    long long gid = (long long)b * 256 + t;
    int g = (int)(gid >> 4);
    int c = ((int)gid & 15) * 8;
    float acc[8] = {0.f,0.f,0.f,0.f,0.f,0.f,0.f,0.f};
    int k = cnt_sd[g];
    gacc_plain(xs_in, adj_sd, off_sd[g], k, c, acc);
    float ic = 1.0f / fmaxf((float)k, 1.0f);
#pragma unroll
    for (int i = 0; i < 8; ++i) acc[i] *= ic;
    st_h8(SA + (size_t)g * H + c, acc);
}

// ---------------- kernel B: fused layer (R4 barrier structure + degree-binned rows) ----------------
__global__ __launch_bounds__(256) void fused_layer(
        const __half* __restrict__ xs_in, const __half* __restrict__ xm_in,
        const __half* __restrict__ SA,
        const int* __restrict__ off_md, const int* __restrict__ cnt_md, const int* __restrict__ adj_md,
        const int* __restrict__ off_ms, const int* __restrict__ cnt_ms, const int* __restrict__ adj_ms,
        const int* __restrict__ off_ss, const int* __restrict__ cnt_ss, const int* __restrict__ adj_ss,
        const int* __restrict__ wl_m, const int* __restrict__ wl_s,
        const float* __restrict__ dvf, const float* __restrict__ dvr,
        const __half* __restrict__ wbuf,
        const float* __restrict__ bl, const float* __restrict__ gb,
        const float* __restrict__ grb, const float* __restrict__ bls,
        __half* __restrict__ xm_out, __half* __restrict__ xs_out, int layer)
{
    __shared__ __half At[4][16][APAD];
    __shared__ int wlr[16];
    const int t = threadIdx.x;
    const int grp = t >> 4;        // row within 16-row tile
    const int c = (t & 15) * 8;    // col chunk (8 halves)
    const size_t HH = (size_t)H * H;
    const bool isM = (int)blockIdx.x < MB_M;

    if (isM) {
        const int r = wl_m[blockIdx.x * 16 + grp];     // degree-binned row id
        if ((t & 15) == 0) wlr[grp] = r;
        // seg0: precomputed SAGE aggregate (linear-in-row read)
        *(half8*)&At[0][grp][c] = *(const half8*)(SA + (size_t)r * H + c);
        // seg1: self row (also used by GCN self-loop terms)
        half8 self = *(const half8*)(xm_in + (size_t)r * H + c);
        *(half8*)&At[1][grp][c] = self;
        // seg2: GCN m2m forward
        float acc[8] = {0.f,0.f,0.f,0.f,0.f,0.f,0.f,0.f};
        gacc_weighted(xm_in, adj_md, dvf, off_md[r], cnt_md[r], c, acc);
        float dd = dvf[r], s2 = dd * dd;
#pragma unroll
        for (int i = 0; i < 8; ++i) acc[i] = dd * acc[i] + s2 * (float)self[i];
        st_h8(&At[2][grp][c], acc);
        // seg3: GCN m2m reverse
#pragma unroll
        for (int i = 0; i < 8; ++i) acc[i] = 0.f;
        gacc_weighted(xm_in, adj_ms, dvr, off_ms[r], cnt_ms[r], c, acc);
        dd = dvr[r]; s2 = dd * dd;
#pragma unroll
        for (int i = 0; i < 8; ++i) acc[i] = dd * acc[i] + s2 * (float)self[i];
        st_h8(&At[3][grp][c], acc);
        __syncthreads();
        // MFMA: wave w computes col-tiles 2w, 2w+1 over all 4 segments
        const int w = t >> 6, lane = t & 63, quad = lane >> 4, nlo = lane & 15;
        floatx4 o0, o1;
        o0[0]=0.f;o0[1]=0.f;o0[2]=0.f;o0[3]=0.f;
        o1[0]=0.f;o1[1]=0.f;o1[2]=0.f;o1[3]=0.f;
        const int t0 = 2 * w, t1 = 2 * w + 1;
#pragma unroll
        for (int seg = 0; seg < 4; ++seg) {
            const __half* Wt = wbuf + (size_t)(seg * 2 + layer) * HH;
#pragma unroll
            for (int k0 = 0; k0 < 128; k0 += 32) {
                half8 a = *(const half8*)&At[seg][nlo][k0 + quad * 8];
                half8 b0 = *(const half8*)(Wt + (size_t)(t0 * 16 + nlo) * H + k0 + quad * 8);
                half8 b1 = *(const half8*)(Wt + (size_t)(t1 * 16 + nlo) * H + k0 + quad * 8);
                o0 = __builtin_amdgcn_mfma_f32_16x16x32_f16(a, b0, o0, 0, 0, 0);
                o1 = __builtin_amdgcn_mfma_f32_16x16x32_f16(a, b1, o1, 0, 0, 0);
            }
        }
#pragma unroll
        for (int u = 0; u < 2; ++u) {
            floatx4 oo = u ? o1 : o0;
            int col = (2 * w + u) * 16 + nlo;
            float bias = bl[col] + gb[col] + grb[col];
#pragma unroll
            for (int i = 0; i < 4; ++i) {
                int rr = wlr[quad * 4 + i];
                xm_out[(size_t)rr * H + col] = __float2half(fmaxf(oo[i] + bias, 0.f));
            }
        }
    } else {
        const int blk = (int)blockIdx.x - MB_M;
        const int r = wl_s[blk * 16 + grp];            // degree-binned row id
        if ((t & 15) == 0) wlr[grp] = r;
        float acc[8] = {0.f,0.f,0.f,0.f,0.f,0.f,0.f,0.f};
        // seg0: SAGE rev mean aggregation from xm
        int k = cnt_ss[r];
        gacc_plain(xm_in, adj_ss, off_ss[r], k, c, acc);
        float ic = 1.0f / fmaxf((float)k, 1.0f);
#pragma unroll
        for (int i = 0; i < 8; ++i) acc[i] *= ic;
        st_h8(&At[0][grp][c], acc);
        // seg1: self row
        *(half8*)&At[1][grp][c] = *(const half8*)(xs_in + (size_t)r * H + c);
        __syncthreads();
        const int w = t >> 6, lane = t & 63, quad = lane >> 4, nlo = lane & 15;
        floatx4 o0, o1;
        o0[0]=0.f;o0[1]=0.f;o0[2]=0.f;o0[3]=0.f;
        o1[0]=0.f;o1[1]=0.f;o1[2]=0.f;o1[3]=0.f;
        const int t0 = 2 * w, t1 = 2 * w + 1;
#pragma unroll
        for (int seg = 0; seg < 2; ++seg) {
            const __half* Wt = wbuf + (size_t)((4 + seg) * 2 + layer) * HH;
#pragma unroll
            for (int k0 = 0; k0 < 128; k0 += 32) {
                half8 a = *(const half8*)&At[seg][nlo][k0 + quad * 8];
                half8 b0 = *(const half8*)(Wt + (size_t)(t0 * 16 + nlo) * H + k0 + quad * 8);
                half8 b1 = *(const half8*)(Wt + (size_t)(t1 * 16 + nlo) * H + k0 + quad * 8);
                o0 = __builtin_amdgcn_mfma_f32_16x16x32_f16(a, b0, o0, 0, 0, 0);
                o1 = __builtin_amdgcn_mfma_f32_16x16x32_f16(a, b1, o1, 0, 0, 0);
            }
        }
#pragma unroll
        for (int u = 0; u < 2; ++u) {
            floatx4 oo = u ? o1 : o0;
            int col = (2 * w + u) * 16 + nlo;
            float bias = bls[col];
#pragma unroll
            for (int i = 0; i < 4; ++i) {
                int rr = wlr[quad * 4 + i];
                xs_out[(size_t)rr * H + col] = __float2half(fmaxf(oo[i] + bias, 0.f));
            }
        }
    }
}

// ---------------- classifier: 16 lanes/pair, half8 (16B) loads ----------------
__global__ void classify(const __half* __restrict__ xs16, const __half* __restrict__ xm16,
                         const int* __restrict__ ls, const int* __restrict__ ld,
                         float* __restrict__ out, int P) {
    long long gid = (long long)blockIdx.x * blockDim.x + threadIdx.x;
    int p = (int)(gid >> 4);
    if (p >= P) return;
    int lane = (int)gid & 15;
    int a = ls[p], b = ld[p];
    half8 u = *(const half8*)(xs16 + (size_t)a * H + lane * 8);
    half8 v = *(const half8*)(xm16 + (size_t)b * H + lane * 8);
    float s = 0.f;
#pragma unroll
    for (int i = 0; i < 8; ++i) s += (float)u[i] * (float)v[i];
    for (int off = 8; off > 0; off >>= 1) s += __shfl_down(s, off, 16);
    if (lane == 0) out[p] = s;
}

// ---------------- host orchestration ----------------
extern "C" void kernel_launch(void* const* d_in, const int* in_sizes, int n_in,
                              void* d_out, int out_size, void* d_ws, size_t ws_size,
                              hipStream_t stream) {
    const int* s2m_src = (const int*)d_in[0];
    const int* s2m_dst = (const int*)d_in[1];
    const int* m2m_src = (const int*)d_in[2];
    const int* m2m_dst = (const int*)d_in[3];
    const int* lbl_src = (const int*)d_in[4];
    const int* lbl_dst = (const int*)d_in[5];
    const float* s_emb = (const float*)d_in[6];
    const float* m_emb = (const float*)d_in[7];
    const float* Wl_s2m = (const float*)d_in[8];
    const float* bl_s2m = (const float*)d_in[9];
    const float* Wr_s2m = (const float*)d_in[10];
    const float* Wl_rev = (const float*)d_in[11];
    const float* bl_rev = (const float*)d_in[12];
    const float* Wr_rev = (const float*)d_in[13];
    const float* gW  = (const float*)d_in[14];
    const float* gb  = (const float*)d_in[15];
    const float* grW = (const float*)d_in[16];
    const float* grb = (const float*)d_in[17];

    __half* hws = (__half*)d_ws;
    size_t ho = 0;
    __half* xm16_a = hws + ho; ho += (size_t)NM * H;
    __half* xm16_b = hws + ho; ho += (size_t)NM * H;
    __half* xs16_a = hws + ho; ho += (size_t)NS * H;
    __half* xs16_b = hws + ho; ho += (size_t)NS * H;
    __half* scratch = hws + ho; ho += (size_t)(3 * NM + NS) * H;  // CSR records, then SA
    __half* wbuf = hws + ho; ho += (size_t)12 * H * H;

    float* fws = (float*)(hws + ho);
    size_t fo = 0;
    float* dvf = fws + fo; fo += NM;
    float* dvr = fws + fo; fo += NM;

    int* ip = (int*)(fws + fo);
    size_t io = 0;
    int* off_sd = ip + io; io += NM;
    int* off_ss = ip + io; io += NS;
    int* off_md = ip + io; io += NM;
    int* off_ms = ip + io; io += NM;
    int* cnt_sd = ip + io; io += NM;
    int* cnt_ss = ip + io; io += NS;
    int* cnt_md = ip + io; io += NM;
    int* cnt_ms = ip + io; io += NM;
    int* bc     = ip + io; io += 4 * 16384;
    int* binCnt  = ip + io; io += 128;   // zeroed with bc
    int* binBase = ip + io; io += 128;
    int* wl_m   = ip + io; io += NM;
    int* wl_s   = ip + io; io += NS;
    int* adj_sd = ip + io; io += NB_SD * CAP_SD;
    int* adj_ss = ip + io; io += NB_SS * CAP_SS;
    int* adj_md = ip + io; io += NB_MD * CAP_MD;
    int* adj_ms = ip + io; io += NB_MS * CAP_MS;

    // packed 4B records aliased onto scratch (dead once place2 finishes; SA reuses this space)
    unsigned int* p_sd = (unsigned int*)scratch;
    unsigned int* p_ss = p_sd + (size_t)NB_SD * CAP_SD;
    unsigned int* p_md = p_ss + (size_t)NB_SS * CAP_SS;
    unsigned int* p_ms = p_md + (size_t)NB_MD * CAP_MD;

    __half* SA = scratch;   // NM*H halves, live only during the layer loop

    // ---- CSR build phase 1 + embeddings/weights prep in ONE dispatch ----
    hipMemsetAsync(bc, 0, (4 * 16384 + 128) * sizeof(int), stream);
    place1_prep<<<P1_BLKS + PB_M + PB_S + PB_W, 256, 0, stream>>>(
        s2m_src, s2m_dst, m2m_src, m2m_dst, bc, p_sd, p_ss, p_md, p_ms,
        m_emb, s_emb, Wl_s2m, Wr_s2m, gW, grW, Wl_rev, Wr_rev,
        xm16_a, xs16_a, wbuf);
    place2_fused<<<NB_SD + NB_SS + NB_MD + NB_MS, 256, 0, stream>>>(
        bc, p_sd, p_ss, p_md, p_ms,
        adj_sd, adj_ss, adj_md, adj_ms,
        off_sd, off_ss, off_md, off_ms,
        cnt_sd, cnt_ss, cnt_md, cnt_ms);

    // ---- degree-bin permutation for fused_layer blocks ----
    bin_hist<<<HB_M + HB_S, 256, 0, stream>>>(cnt_md, cnt_ms, cnt_ss, binCnt);
    bin_scan<<<1, 128, 0, stream>>>(binCnt, binBase);
    bin_scatter<<<HB_M + HB_S, 256, 0, stream>>>(cnt_md, cnt_ms, cnt_ss, binBase, wl_m, wl_s);

    const __half* xin_m = xm16_a;
    const __half* xin_s = xs16_a;
    __half* xout_m = xm16_b;
    __half* xout_s = xs16_b;

    for (int l = 0; l < 2; ++l) {
        const size_t bo = (size_t)l * H;
        // SAGE s2m gather (+ dinv finalize blocks; idempotent, ready before fused_layer)
        sage_sd_fin<<<SD_GBLK + FIN_BLK, 256, 0, stream>>>(
            xin_s, off_sd, cnt_sd, adj_sd, cnt_md, cnt_ms, SA, dvf, dvr);
        fused_layer<<<MB_M + MB_S, 256, 0, stream>>>(
            xin_s, xin_m, SA,
            off_md, cnt_md, adj_md,
            off_ms, cnt_ms, adj_ms,
            off_ss, cnt_ss, adj_ss,
            wl_m, wl_s,
            dvf, dvr, wbuf,
            bl_s2m + bo, gb + bo, grb + bo, bl_rev + bo,
            xout_m, xout_s, l);
        const __half* tm = xin_m; xin_m = xout_m; xout_m = (__half*)tm;
        const __half* ts = xin_s; xin_s = xout_s; xout_s = (__half*)ts;
    }

    classify<<<(int)(((long long)EL * 16 + 255) / 256), 256, 0, stream>>>(
        xin_s, xin_m, lbl_src, lbl_dst, (float*)d_out, EL);
}

// Round 11
// 825.002 us; speedup vs baseline: 1.0358x; 1.0358x over previous
//
#include <hip/hip_runtime.h>
#include <hip/hip_fp16.h>

#define NS 20000
#define NM 100000
#define H  128
#define ES 1000000
#define EM 2000000
#define EL 500000

#define SH_M 7
#define SH_S 6
#define NB_SD 782
#define NB_SS 313
#define NB_MD 782
#define NB_MS 782
#define CAP_SD 1664
#define CAP_SS 3904
#define CAP_MD 3200
#define CAP_MS 3200
#define MAXCAP 3904
#define CHUNK 4096
#define B_SD ((ES + CHUNK - 1) / CHUNK)
#define B_SS ((ES + CHUNK - 1) / CHUNK)
#define B_MD ((EM + CHUNK - 1) / CHUNK)
#define B_MS ((EM + CHUNK - 1) / CHUNK)
#define VAL_MASK 0x1FFFF

// fused layer geometry (R4-proven): 16 output rows per block, barrier structure
#define MB_M (NM / 16)     // 6250
#define MB_S (NS / 16)     // 1250
#define APAD 136           // LDS A-tile row stride in halves

// merged place1+prep grid sections
#define P1_BLKS (B_SD + B_SS + B_MD + B_MS)   // 1468 sort blocks
#define PB_M 12500         // NM*H/4 / 256
#define PB_S 2500          // NS*H/4 / 256
#define PB_W 768           // 12*H*H / 256

// sage_sd + finalize grid sections
#define SD_GBLK (NM * 16 / 256)    // 6250
#define FIN_BLK ((NM + 255) / 256) // 391

typedef _Float16 half8 __attribute__((ext_vector_type(8)));
typedef float floatx4 __attribute__((ext_vector_type(4)));

// ---------------- CSR build phase 1 + independent prep work in one dispatch ----------------
// Blocks [0, P1_BLKS): block-local counting sort (unchanged logic).
// Blocks [P1_BLKS, +PB_M): fp32->fp16 xm conversion; then xs; then weight transpose.
// The prep sections depend only on kernel inputs, so they co-run with the sort.
__global__ __launch_bounds__(256) void place1_prep(
        const int* __restrict__ s2m_src, const int* __restrict__ s2m_dst,
        const int* __restrict__ m2m_src, const int* __restrict__ m2m_dst,
        int* __restrict__ bc,
        unsigned int* __restrict__ p_sd, unsigned int* __restrict__ p_ss,
        unsigned int* __restrict__ p_md, unsigned int* __restrict__ p_ms,
        const float* __restrict__ m_emb, const float* __restrict__ s_emb,
        const float* __restrict__ w0, const float* __restrict__ w1,
        const float* __restrict__ w2, const float* __restrict__ w3,
        const float* __restrict__ w4, const float* __restrict__ w5,
        __half* __restrict__ xm16, __half* __restrict__ xs16,
        __half* __restrict__ wbuf) {
    __shared__ unsigned int rec[CHUNK];
    __shared__ unsigned short eb[CHUNK];
    __shared__ int cnt[1024];
    __shared__ int gbase[1024];

    int b = blockIdx.x;
    int t = threadIdx.x;

    if (b >= P1_BLKS) {
        int pb = b - P1_BLKS;
        if (pb < PB_M) {
            long long i = (long long)pb * 256 + t;
            float4 v = *(const float4*)&m_emb[i * 4];
            __half2 h0 = __floats2half2_rn(v.x, v.y);
            __half2 h1 = __floats2half2_rn(v.z, v.w);
            __half2* o = (__half2*)&xm16[i * 4];
            o[0] = h0; o[1] = h1;
        } else if (pb < PB_M + PB_S) {
            long long i = (long long)(pb - PB_M) * 256 + t;
            float4 v = *(const float4*)&s_emb[i * 4];
            __half2 h0 = __floats2half2_rn(v.x, v.y);
            __half2 h1 = __floats2half2_rn(v.z, v.w);
            __half2* o = (__half2*)&xs16[i * 4];
            o[0] = h0; o[1] = h1;
        } else {
            int idx = (pb - PB_M - PB_S) * 256 + t;
            int mat = idx / (H * H);
            int rem = idx % (H * H);
            int n = rem / H;
            int k = rem % H;
            const float* base;
            switch (mat >> 1) {
            case 0: base = w0; break; case 1: base = w1; break; case 2: base = w2; break;
            case 3: base = w3; break; case 4: base = w4; break; default: base = w5; break;
            }
            base += (size_t)(mat & 1) * H * H;
            wbuf[(size_t)mat * H * H + (size_t)n * H + k] = __float2half(base[(size_t)k * H + n]);
        }
        return;
    }

    const int *keys, *vals; int shift, cap, E, bcoff; unsigned int* pp;
    int cb;
    if (b < B_SD)                    { cb = b;                      keys = s2m_dst; vals = s2m_src; shift = SH_M; cap = CAP_SD; E = ES; bcoff = 0;     pp = p_sd; }
    else if (b < B_SD+B_SS)          { cb = b - B_SD;               keys = s2m_src; vals = s2m_dst; shift = SH_S; cap = CAP_SS; E = ES; bcoff = 16384; pp = p_ss; }
    else if (b < B_SD+B_SS+B_MD)     { cb = b - B_SD - B_SS;        keys = m2m_dst; vals = m2m_src; shift = SH_M; cap = CAP_MD; E = EM; bcoff = 32768; pp = p_md; }
    else                             { cb = b - B_SD - B_SS - B_MD; keys = m2m_src; vals = m2m_dst; shift = SH_M; cap = CAP_MS; E = EM; bcoff = 49152; pp = p_ms; }
    int* bcp = bc + bcoff;

    int e0 = cb * CHUNK;
    int nv = E - e0; if (nv > CHUNK) nv = CHUNK;

    for (int i = t; i < nv; i += 256) {
        int k = keys[e0 + i];
        int v = vals[e0 + i];
        int bkt = k >> shift;
        rec[i] = ((unsigned int)(k - (bkt << shift)) << 17) | (unsigned int)v;
        eb[i] = (unsigned short)bkt;
    }
#pragma unroll
    for (int j = 0; j < 4; ++j) cnt[t * 4 + j] = 0;
    __syncthreads();
    for (int i = t; i < nv; i += 256) atomicAdd(&cnt[eb[i]], 1);
    __syncthreads();
#pragma unroll
    for (int j = 0; j < 4; ++j) {
        int bk = t * 4 + j;
        int c = cnt[bk];
        if (c > 0) {
            gbase[bk] = atomicAdd(&bcp[bk << 4], c);
            cnt[bk] = 0;
        }
    }
    __syncthreads();
    for (int i = t; i < nv; i += 256) {
        int bk = eb[i];
        int pos = atomicAdd(&cnt[bk], 1);
        int o = gbase[bk] + pos;
        if (o < cap) pp[(size_t)bk * cap + o] = rec[i];
    }
}

// phase 2: fixed-stride adjacency (bucket b owns [b*cap, ...)) — unchanged
__global__ __launch_bounds__(256) void place2_fused(
        const int* __restrict__ bc,
        const unsigned int* __restrict__ p_sd, const unsigned int* __restrict__ p_ss,
        const unsigned int* __restrict__ p_md, const unsigned int* __restrict__ p_ms,
        int* __restrict__ adj_sd, int* __restrict__ adj_ss,
        int* __restrict__ adj_md, int* __restrict__ adj_ms,
        int* __restrict__ off_sd, int* __restrict__ off_ss,
        int* __restrict__ off_md, int* __restrict__ off_ms,
        int* __restrict__ cnt_sd, int* __restrict__ cnt_ss,
        int* __restrict__ cnt_md, int* __restrict__ cnt_ms) {
    __shared__ unsigned int lp[MAXCAP];
    __shared__ int hist[128], cur[128], sbuf[128];
    int b = blockIdx.x;
    int c, lb;
    if (b < NB_SD)                    { c = 0; lb = b; }
    else if (b < NB_SD+NB_SS)         { c = 1; lb = b - NB_SD; }
    else if (b < NB_SD+NB_SS+NB_MD)   { c = 2; lb = b - NB_SD - NB_SS; }
    else                              { c = 3; lb = b - NB_SD - NB_SS - NB_MD; }
    const unsigned int* pp; int *adj, *offp, *cntp; int shift, cap, n;
    switch (c) {
    case 0:  pp = p_sd; adj = adj_sd; offp = off_sd; cntp = cnt_sd; shift = SH_M; cap = CAP_SD; n = NM; break;
    case 1:  pp = p_ss; adj = adj_ss; offp = off_ss; cntp = cnt_ss; shift = SH_S; cap = CAP_SS; n = NS; break;
    case 2:  pp = p_md; adj = adj_md; offp = off_md; cntp = cnt_md; shift = SH_M; cap = CAP_MD; n = NM; break;
    default: pp = p_ms; adj = adj_ms; offp = off_ms; cntp = cnt_ms; shift = SH_M; cap = CAP_MS; n = NM; break;
    }
    int t = threadIdx.x;
    int k = bc[c * 16384 + (lb << 4)];
    if (k > cap) k = cap;
    int base = lb << shift;
    int npb = 1 << shift;
    int bb = lb * cap;   // fixed-stride region
    for (int i = t; i < k; i += 256) lp[i] = pp[(size_t)lb * cap + i];
    if (t < npb) hist[t] = 0;
    __syncthreads();
    for (int i = t; i < k; i += 256) atomicAdd(&hist[lp[i] >> 17], 1);
    __syncthreads();
    int v = (t < npb) ? hist[t] : 0;
    if (t < 128) sbuf[t] = v;
    __syncthreads();
    for (int d = 1; d < 128; d <<= 1) {
        int x = 0;
        if (t >= d && t < 128) x = sbuf[t - d];
        __syncthreads();
        if (t >= d && t < 128) sbuf[t] += x;
        __syncthreads();
    }
    if (t < npb) {
        int excl = sbuf[t] - v;
        cur[t] = excl;
        int node = base + t;
        if (node < n) { offp[node] = bb + excl; cntp[node] = v; }
    }
    __syncthreads();
    for (int i = t; i < k; i += 256) {
        unsigned int p = lp[i];
        int pos = atomicAdd(&cur[p >> 17], 1);
        adj[(size_t)bb + pos] = (int)(p & VAL_MASK);
    }
}

// ---------------- gather primitives: 16 lanes/row, half8 loads, unroll 8 (R0-proven) ----------------
__device__ __forceinline__ void gacc_plain(const __half* __restrict__ X,
                                           const int* __restrict__ adj,
                                           int o, int k, int c, float (&acc)[8]) {
    int j = 0;
    for (; j + 8 <= k; j += 8) {
        int s0 = adj[o+j+0], s1 = adj[o+j+1], s2 = adj[o+j+2], s3 = adj[o+j+3];
        int s4 = adj[o+j+4], s5 = adj[o+j+5], s6 = adj[o+j+6], s7 = adj[o+j+7];
        half8 v0 = *(const half8*)(X + (size_t)s0 * H + c);
        half8 v1 = *(const half8*)(X + (size_t)s1 * H + c);
        half8 v2 = *(const half8*)(X + (size_t)s2 * H + c);
        half8 v3 = *(const half8*)(X + (size_t)s3 * H + c);
        half8 v4 = *(const half8*)(X + (size_t)s4 * H + c);
        half8 v5 = *(const half8*)(X + (size_t)s5 * H + c);
        half8 v6 = *(const half8*)(X + (size_t)s6 * H + c);
        half8 v7 = *(const half8*)(X + (size_t)s7 * H + c);
#pragma unroll
        for (int i = 0; i < 8; ++i)
            acc[i] += (float)v0[i] + (float)v1[i] + (float)v2[i] + (float)v3[i]
                    + (float)v4[i] + (float)v5[i] + (float)v6[i] + (float)v7[i];
    }
    for (; j + 4 <= k; j += 4) {
        int s0 = adj[o+j+0], s1 = adj[o+j+1], s2 = adj[o+j+2], s3 = adj[o+j+3];
        half8 v0 = *(const half8*)(X + (size_t)s0 * H + c);
        half8 v1 = *(const half8*)(X + (size_t)s1 * H + c);
        half8 v2 = *(const half8*)(X + (size_t)s2 * H + c);
        half8 v3 = *(const half8*)(X + (size_t)s3 * H + c);
#pragma unroll
        for (int i = 0; i < 8; ++i)
            acc[i] += (float)v0[i] + (float)v1[i] + (float)v2[i] + (float)v3[i];
    }
    for (; j < k; ++j) {
        int s = adj[o + j];
        half8 v = *(const half8*)(X + (size_t)s * H + c);
#pragma unroll
        for (int i = 0; i < 8; ++i) acc[i] += (float)v[i];
    }
}

__device__ __forceinline__ void gacc_weighted(const __half* __restrict__ X,
                                              const int* __restrict__ adj,
                                              const float* __restrict__ dinv,
                                              int o, int k, int c, float (&acc)[8]) {
    int j = 0;
    for (; j + 8 <= k; j += 8) {
        int s0 = adj[o+j+0], s1 = adj[o+j+1], s2 = adj[o+j+2], s3 = adj[o+j+3];
        int s4 = adj[o+j+4], s5 = adj[o+j+5], s6 = adj[o+j+6], s7 = adj[o+j+7];
        float d0 = dinv[s0], d1 = dinv[s1], d2 = dinv[s2], d3 = dinv[s3];
        float d4 = dinv[s4], d5 = dinv[s5], d6 = dinv[s6], d7 = dinv[s7];
        half8 v0 = *(const half8*)(X + (size_t)s0 * H + c);
        half8 v1 = *(const half8*)(X + (size_t)s1 * H + c);
        half8 v2 = *(const half8*)(X + (size_t)s2 * H + c);
        half8 v3 = *(const half8*)(X + (size_t)s3 * H + c);
        half8 v4 = *(const half8*)(X + (size_t)s4 * H + c);
        half8 v5 = *(const half8*)(X + (size_t)s5 * H + c);
        half8 v6 = *(const half8*)(X + (size_t)s6 * H + c);
        half8 v7 = *(const half8*)(X + (size_t)s7 * H + c);
#pragma unroll
        for (int i = 0; i < 8; ++i)
            acc[i] += d0 * (float)v0[i] + d1 * (float)v1[i] + d2 * (float)v2[i] + d3 * (float)v3[i]
                    + d4 * (float)v4[i] + d5 * (float)v5[i] + d6 * (float)v6[i] + d7 * (float)v7[i];
    }
    for (; j + 4 <= k; j += 4) {
        int s0 = adj[o+j+0], s1 = adj[o+j+1], s2 = adj[o+j+2], s3 = adj[o+j+3];
        float d0 = dinv[s0], d1 = dinv[s1], d2 = dinv[s2], d3 = dinv[s3];
        half8 v0 = *(const half8*)(X + (size_t)s0 * H + c);
        half8 v1 = *(const half8*)(X + (size_t)s1 * H + c);
        half8 v2 = *(const half8*)(X + (size_t)s2 * H + c);
        half8 v3 = *(const half8*)(X + (size_t)s3 * H + c);
#pragma unroll
        for (int i = 0; i < 8; ++i)
            acc[i] += d0 * (float)v0[i] + d1 * (float)v1[i] + d2 * (float)v2[i] + d3 * (float)v3[i];
    }
    for (; j < k; ++j) {
        int s = adj[o + j];
        float ds = dinv[s];
        half8 v = *(const half8*)(X + (size_t)s * H + c);
#pragma unroll
        for (int i = 0; i < 8; ++i) acc[i] += ds * (float)v[i];
    }
}

__device__ __forceinline__ void st_h8(__half* p, const float (&a)[8]) {
    half8 h;
#pragma unroll
    for (int i = 0; i < 8; ++i) h[i] = (_Float16)a[i];
    *(half8*)p = h;
}

// ---------------- kernel A: SAGE s2m gather (xs only) + dinv finalize blocks ----------------
__global__ __launch_bounds__(256) void sage_sd_fin(
        const __half* __restrict__ xs_in,
        const int* __restrict__ off_sd, const int* __restrict__ cnt_sd,
        const int* __restrict__ adj_sd,
        const int* __restrict__ c_md, const int* __restrict__ c_ms,
        __half* __restrict__ SA, float* __restrict__ dvf, float* __restrict__ dvr) {
    int b = blockIdx.x, t = threadIdx.x;
    if (b >= SD_GBLK) {
        int i = (b - SD_GBLK) * 256 + t;
        if (i < NM) {
            dvf[i] = rsqrtf((float)c_md[i] + 1.0f);
            dvr[i] = rsqrtf((float)c_ms[i] + 1.0f);
        }
        return;
    }
    long long gid = (long long)b * 256 + t;
    int g = (int)(gid >> 4);
    int c = ((int)gid & 15) * 8;
    float acc[8] = {0.f,0.f,0.f,0.f,0.f,0.f,0.f,0.f};
    int k = cnt_sd[g];
    gacc_plain(xs_in, adj_sd, off_sd[g], k, c, acc);
    float ic = 1.0f / fmaxf((float)k, 1.0f);
#pragma unroll
    for (int i = 0; i < 8; ++i) acc[i] *= ic;
    st_h8(SA + (size_t)g * H + c, acc);
}

// ---------------- kernel B: fused layer (R4-verified barrier structure) ----------------
__global__ __launch_bounds__(256) void fused_layer(
        const __half* __restrict__ xs_in, const __half* __restrict__ xm_in,
        const __half* __restrict__ SA,
        const int* __restrict__ off_md, const int* __restrict__ cnt_md, const int* __restrict__ adj_md,
        const int* __restrict__ off_ms, const int* __restrict__ cnt_ms, const int* __restrict__ adj_ms,
        const int* __restrict__ off_ss, const int* __restrict__ cnt_ss, const int* __restrict__ adj_ss,
        const float* __restrict__ dvf, const float* __restrict__ dvr,
        const __half* __restrict__ wbuf,
        const float* __restrict__ bl, const float* __restrict__ gb,
        const float* __restrict__ grb, const float* __restrict__ bls,
        __half* __restrict__ xm_out, __half* __restrict__ xs_out, int layer)
{
    __shared__ __half At[4][16][APAD];
    const int t = threadIdx.x;
    const int grp = t >> 4;        // row within 16-row tile
    const int c = (t & 15) * 8;    // col chunk (8 halves)
    const size_t HH = (size_t)H * H;
    const bool isM = (int)blockIdx.x < MB_M;

    if (isM) {
        const int r = blockIdx.x * 16 + grp;           // NM % 16 == 0
        // seg0: precomputed SAGE aggregate (linear read)
        *(half8*)&At[0][grp][c] = *(const half8*)(SA + (size_t)r * H + c);
        // seg1: self row (also used by GCN self-loop terms)
        half8 self = *(const half8*)(xm_in + (size_t)r * H + c);
        *(half8*)&At[1][grp][c] = self;
        // seg2: GCN m2m forward
        float acc[8] = {0.f,0.f,0.f,0.f,0.f,0.f,0.f,0.f};
        gacc_weighted(xm_in, adj_md, dvf, off_md[r], cnt_md[r], c, acc);
        float dd = dvf[r], s2 = dd * dd;
#pragma unroll
        for (int i = 0; i < 8; ++i) acc[i] = dd * acc[i] + s2 * (float)self[i];
        st_h8(&At[2][grp][c], acc);
        // seg3: GCN m2m reverse
#pragma unroll
        for (int i = 0; i < 8; ++i) acc[i] = 0.f;
        gacc_weighted(xm_in, adj_ms, dvr, off_ms[r], cnt_ms[r], c, acc);
        dd = dvr[r]; s2 = dd * dd;
#pragma unroll
        for (int i = 0; i < 8; ++i) acc[i] = dd * acc[i] + s2 * (float)self[i];
        st_h8(&At[3][grp][c], acc);
        __syncthreads();
        // MFMA: wave w computes col-tiles 2w, 2w+1 over all 4 segments
        const int w = t >> 6, lane = t & 63, quad = lane >> 4, nlo = lane & 15;
        floatx4 o0, o1;
        o0[0]=0.f;o0[1]=0.f;o0[2]=0.f;o0[3]=0.f;
        o1[0]=0.f;o1[1]=0.f;o1[2]=0.f;o1[3]=0.f;
        const int t0 = 2 * w, t1 = 2 * w + 1;
#pragma unroll
        for (int seg = 0; seg < 4; ++seg) {
            const __half* Wt = wbuf + (size_t)(seg * 2 + layer) * HH;
#pragma unroll
            for (int k0 = 0; k0 < 128; k0 += 32) {
                half8 a = *(const half8*)&At[seg][nlo][k0 + quad * 8];
                half8 b0 = *(const half8*)(Wt + (size_t)(t0 * 16 + nlo) * H + k0 + quad * 8);
                half8 b1 = *(const half8*)(Wt + (size_t)(t1 * 16 + nlo) * H + k0 + quad * 8);
                o0 = __builtin_amdgcn_mfma_f32_16x16x32_f16(a, b0, o0, 0, 0, 0);
                o1 = __builtin_amdgcn_mfma_f32_16x16x32_f16(a, b1, o1, 0, 0, 0);
            }
        }
        const int bm = blockIdx.x * 16;
#pragma unroll
        for (int u = 0; u < 2; ++u) {
            floatx4 oo = u ? o1 : o0;
            int col = (2 * w + u) * 16 + nlo;
            float bias = bl[col] + gb[col] + grb[col];
#pragma unroll
            for (int i = 0; i < 4; ++i) {
                int rr = bm + quad * 4 + i;
                xm_out[(size_t)rr * H + col] = __float2half(fmaxf(oo[i] + bias, 0.f));
            }
        }
    } else {
        const int blk = (int)blockIdx.x - MB_M;
        const int r = blk * 16 + grp;                  // NS % 16 == 0
        float acc[8] = {0.f,0.f,0.f,0.f,0.f,0.f,0.f,0.f};
        // seg0: SAGE rev mean aggregation from xm
        int k = cnt_ss[r];
        gacc_plain(xm_in, adj_ss, off_ss[r], k, c, acc);
        float ic = 1.0f / fmaxf((float)k, 1.0f);
#pragma unroll
        for (int i = 0; i < 8; ++i) acc[i] *= ic;
        st_h8(&At[0][grp][c], acc);
        // seg1: self row
        *(half8*)&At[1][grp][c] = *(const half8*)(xs_in + (size_t)r * H + c);
        __syncthreads();
        const int w = t >> 6, lane = t & 63, quad = lane >> 4, nlo = lane & 15;
        floatx4 o0, o1;
        o0[0]=0.f;o0[1]=0.f;o0[2]=0.f;o0[3]=0.f;
        o1[0]=0.f;o1[1]=0.f;o1[2]=0.f;o1[3]=0.f;
        const int t0 = 2 * w, t1 = 2 * w + 1;
#pragma unroll
        for (int seg = 0; seg < 2; ++seg) {
            const __half* Wt = wbuf + (size_t)((4 + seg) * 2 + layer) * HH;
#pragma unroll
            for (int k0 = 0; k0 < 128; k0 += 32) {
                half8 a = *(const half8*)&At[seg][nlo][k0 + quad * 8];
                half8 b0 = *(const half8*)(Wt + (size_t)(t0 * 16 + nlo) * H + k0 + quad * 8);
                half8 b1 = *(const half8*)(Wt + (size_t)(t1 * 16 + nlo) * H + k0 + quad * 8);
                o0 = __builtin_amdgcn_mfma_f32_16x16x32_f16(a, b0, o0, 0, 0, 0);
                o1 = __builtin_amdgcn_mfma_f32_16x16x32_f16(a, b1, o1, 0, 0, 0);
            }
        }
        const int bm = blk * 16;
#pragma unroll
        for (int u = 0; u < 2; ++u) {
            floatx4 oo = u ? o1 : o0;
            int col = (2 * w + u) * 16 + nlo;
            float bias = bls[col];
#pragma unroll
            for (int i = 0; i < 4; ++i) {
                int rr = bm + quad * 4 + i;
                xs_out[(size_t)rr * H + col] = __float2half(fmaxf(oo[i] + bias, 0.f));
            }
        }
    }
}

// ---------------- classifier: 16 lanes/pair, half8 (16B) loads ----------------
__global__ void classify(const __half* __restrict__ xs16, const __half* __restrict__ xm16,
                         const int* __restrict__ ls, const int* __restrict__ ld,
                         float* __restrict__ out, int P) {
    long long gid = (long long)blockIdx.x * blockDim.x + threadIdx.x;
    int p = (int)(gid >> 4);
    if (p >= P) return;
    int lane = (int)gid & 15;
    int a = ls[p], b = ld[p];
    half8 u = *(const half8*)(xs16 + (size_t)a * H + lane * 8);
    half8 v = *(const half8*)(xm16 + (size_t)b * H + lane * 8);
    float s = 0.f;
#pragma unroll
    for (int i = 0; i < 8; ++i) s += (float)u[i] * (float)v[i];
    for (int off = 8; off > 0; off >>= 1) s += __shfl_down(s, off, 16);
    if (lane == 0) out[p] = s;
}

// ---------------- host orchestration ----------------
extern "C" void kernel_launch(void* const* d_in, const int* in_sizes, int n_in,
                              void* d_out, int out_size, void* d_ws, size_t ws_size,
                              hipStream_t stream) {
    const int* s2m_src = (const int*)d_in[0];
    const int* s2m_dst = (const int*)d_in[1];
    const int* m2m_src = (const int*)d_in[2];
    const int* m2m_dst = (const int*)d_in[3];
    const int* lbl_src = (const int*)d_in[4];
    const int* lbl_dst = (const int*)d_in[5];
    const float* s_emb = (const float*)d_in[6];
    const float* m_emb = (const float*)d_in[7];
    const float* Wl_s2m = (const float*)d_in[8];
    const float* bl_s2m = (const float*)d_in[9];
    const float* Wr_s2m = (const float*)d_in[10];
    const float* Wl_rev = (const float*)d_in[11];
    const float* bl_rev = (const float*)d_in[12];
    const float* Wr_rev = (const float*)d_in[13];
    const float* gW  = (const float*)d_in[14];
    const float* gb  = (const float*)d_in[15];
    const float* grW = (const float*)d_in[16];
    const float* grb = (const float*)d_in[17];

    __half* hws = (__half*)d_ws;
    size_t ho = 0;
    __half* xm16_a = hws + ho; ho += (size_t)NM * H;
    __half* xm16_b = hws + ho; ho += (size_t)NM * H;
    __half* xs16_a = hws + ho; ho += (size_t)NS * H;
    __half* xs16_b = hws + ho; ho += (size_t)NS * H;
    __half* scratch = hws + ho; ho += (size_t)(3 * NM + NS) * H;  // CSR records, then SA
    __half* wbuf = hws + ho; ho += (size_t)12 * H * H;

    float* fws = (float*)(hws + ho);
    size_t fo = 0;
    float* dvf = fws + fo; fo += NM;
    float* dvr = fws + fo; fo += NM;

    int* ip = (int*)(fws + fo);
    size_t io = 0;
    int* off_sd = ip + io; io += NM;
    int* off_ss = ip + io; io += NS;
    int* off_md = ip + io; io += NM;
    int* off_ms = ip + io; io += NM;
    int* cnt_sd = ip + io; io += NM;
    int* cnt_ss = ip + io; io += NS;
    int* cnt_md = ip + io; io += NM;
    int* cnt_ms = ip + io; io += NM;
    int* bc     = ip + io; io += 4 * 16384;
    int* adj_sd = ip + io; io += NB_SD * CAP_SD;
    int* adj_ss = ip + io; io += NB_SS * CAP_SS;
    int* adj_md = ip + io; io += NB_MD * CAP_MD;
    int* adj_ms = ip + io; io += NB_MS * CAP_MS;

    // packed 4B records aliased onto scratch (dead once place2 finishes; SA reuses this space)
    unsigned int* p_sd = (unsigned int*)scratch;
    unsigned int* p_ss = p_sd + (size_t)NB_SD * CAP_SD;
    unsigned int* p_md = p_ss + (size_t)NB_SS * CAP_SS;
    unsigned int* p_ms = p_md + (size_t)NB_MD * CAP_MD;

    __half* SA = scratch;   // NM*H halves, live only during the layer loop

    // ---- CSR build phase 1 + embeddings/weights prep in ONE dispatch ----
    hipMemsetAsync(bc, 0, 4 * 16384 * sizeof(int), stream);
    place1_prep<<<P1_BLKS + PB_M + PB_S + PB_W, 256, 0, stream>>>(
        s2m_src, s2m_dst, m2m_src, m2m_dst, bc, p_sd, p_ss, p_md, p_ms,
        m_emb, s_emb, Wl_s2m, Wr_s2m, gW, grW, Wl_rev, Wr_rev,
        xm16_a, xs16_a, wbuf);
    place2_fused<<<NB_SD + NB_SS + NB_MD + NB_MS, 256, 0, stream>>>(
        bc, p_sd, p_ss, p_md, p_ms,
        adj_sd, adj_ss, adj_md, adj_ms,
        off_sd, off_ss, off_md, off_ms,
        cnt_sd, cnt_ss, cnt_md, cnt_ms);

    const __half* xin_m = xm16_a;
    const __half* xin_s = xs16_a;
    __half* xout_m = xm16_b;
    __half* xout_s = xs16_b;

    for (int l = 0; l < 2; ++l) {
        const size_t bo = (size_t)l * H;
        // SAGE s2m gather (+ dinv finalize blocks; idempotent, ready before fused_layer)
        sage_sd_fin<<<SD_GBLK + FIN_BLK, 256, 0, stream>>>(
            xin_s, off_sd, cnt_sd, adj_sd, cnt_md, cnt_ms, SA, dvf, dvr);
        fused_layer<<<MB_M + MB_S, 256, 0, stream>>>(
            xin_s, xin_m, SA,
            off_md, cnt_md, adj_md,
            off_ms, cnt_ms, adj_ms,
            off_ss, cnt_ss, adj_ss,
            dvf, dvr, wbuf,
            bl_s2m + bo, gb + bo, grb + bo, bl_rev + bo,
            xout_m, xout_s, l);
        const __half* tm = xin_m; xin_m = xout_m; xout_m = (__half*)tm;
        const __half* ts = xin_s; xin_s = xout_s; xout_s = (__half*)ts;
    }

    classify<<<(int)(((long long)EL * 16 + 255) / 256), 256, 0, stream>>>(
        xin_s, xin_m, lbl_src, lbl_dst, (float*)d_out, EL);
}